// Round 4
// baseline (285.769 us; speedup 1.0000x reference)
//
#include <hip/hip_runtime.h>
#include <hip/hip_bf16.h>
#include <math.h>

// ---------- helpers ----------
__device__ __forceinline__ unsigned short f2bf(float f) {
    union { float f; unsigned u; } c; c.f = f;
    unsigned r = c.u + 0x7fffu + ((c.u >> 16) & 1u);
    return (unsigned short)(r >> 16);
}
__device__ __forceinline__ float bfu(unsigned short u) {
    union { unsigned x; float f; } c; c.x = ((unsigned)u) << 16; return c.f;
}
__device__ __forceinline__ float gelu_t(float x) {
    float z = x * (1.59576912f + 0.07135481f * x * x);
    return x / (1.0f + __expf(-z));
}

typedef __bf16 bf16x8_t __attribute__((ext_vector_type(8)));
typedef float  f32x4_t  __attribute__((ext_vector_type(4)));
typedef unsigned short u16x8 __attribute__((ext_vector_type(8)));

#define AS1 __attribute__((address_space(1)))
#define AS3 __attribute__((address_space(3)))
__device__ __forceinline__ void g2lds16(const void* g, void* l) {
    __builtin_amdgcn_global_load_lds((const AS1 unsigned int*)g, (AS3 unsigned int*)l, 16, 0, 0);
}

// ---------- all weights fp32 -> bf16; w1 pre-scaled by ln2 gamma (LN fold) ----------
__global__ void cvt_all(const float* __restrict__ wq, const float* __restrict__ wk,
                        const float* __restrict__ wv, const float* __restrict__ wo,
                        const float* __restrict__ w1, const float* __restrict__ w2,
                        const float* __restrict__ ln2g,
                        unsigned short* __restrict__ wqkv_b, unsigned short* __restrict__ wo_b,
                        unsigned short* __restrict__ w1_b, unsigned short* __restrict__ w2_b) {
    int i = blockIdx.x * 256 + threadIdx.x;   // float4 units
    const float* src; unsigned short* dst; int base; int isw1 = 0;
    if (i < 16384)       { src = wq; dst = wqkv_b;          base = 0; }
    else if (i < 32768)  { src = wk; dst = wqkv_b + 65536;  base = 16384; }
    else if (i < 49152)  { src = wv; dst = wqkv_b + 131072; base = 32768; }
    else if (i < 65536)  { src = wo; dst = wo_b;            base = 49152; }
    else if (i < 131072) { src = w1; dst = w1_b;            base = 65536; isw1 = 1; }
    else                 { src = w2; dst = w2_b;            base = 131072; }
    int j = (i - base) * 4;
    float4 v = *(const float4*)(src + j);
    if (isw1) {   // fold ln2 gamma into w1 columns (k = j & 255; rows are 256 wide)
        float4 g = *(const float4*)(ln2g + (j & 255));
        v.x *= g.x; v.y *= g.y; v.z *= g.z; v.w *= g.w;
    }
    ushort4 o = { f2bf(v.x), f2bf(v.y), f2bf(v.z), f2bf(v.w) };
    *(ushort4*)(dst + j) = o;
}

// ---------- precompute LN2-fold row sums: s1[n]=sum_k g[k]*w1[n][k]; b1p[n]=b1[n]+sum_k b[k]*w1[n][k]
__global__ void prep_mlp(const float* __restrict__ w1, const float* __restrict__ ln2g,
                         const float* __restrict__ ln2b, const float* __restrict__ b1,
                         float* __restrict__ s1, float* __restrict__ b1p) {
    int n = blockIdx.x * 256 + threadIdx.x;   // 0..1023
    const float* wr = w1 + (size_t)n * 256;
    float ss = 0.f, sb = 0.f;
    #pragma unroll 4
    for (int k = 0; k < 256; k += 4) {
        float4 w = *(const float4*)(wr + k);
        float4 g = *(const float4*)(ln2g + k);
        float4 b = *(const float4*)(ln2b + k);
        ss += w.x * g.x + w.y * g.y + w.z * g.z + w.w * g.w;
        sb += w.x * b.x + w.y * b.y + w.z * b.z + w.w * b.w;
    }
    s1[n] = ss;
    b1p[n] = b1[n] + sb;
}

// ---------- LayerNorm; GATHER=1 fuses shift+window-partition ----------
template<int GATHER, int BF16IN>
__global__ void ln_kernel(const void* __restrict__ xv, const float* __restrict__ g,
                          const float* __restrict__ b, unsigned short* __restrict__ out) {
    int row  = blockIdx.x * 4 + (threadIdx.x >> 6);
    int lane = threadIdx.x & 63;
    int src;
    if (GATHER) {
        int bb = row >> 12;
        int rem = row & 4095;
        int winid = rem >> 6, tok = rem & 63;
        int wi = winid >> 3, wj = winid & 7;
        int ii = tok >> 3,  jj = tok & 7;
        int hh = (wi * 8 + ii + 4) & 63;     // roll(-4)
        int ww = (wj * 8 + jj + 4) & 63;
        src = (bb << 12) + hh * 64 + ww;
    } else {
        src = row;
    }
    float4 v;
    if (BF16IN) {
        ushort4 u = *(const ushort4*)((const unsigned short*)xv + (size_t)src * 256 + lane * 4);
        v.x = bfu(u.x); v.y = bfu(u.y); v.z = bfu(u.z); v.w = bfu(u.w);
    } else {
        v = *(const float4*)((const float*)xv + (size_t)src * 256 + lane * 4);
    }
    float s  = v.x + v.y + v.z + v.w;
    float s2 = v.x*v.x + v.y*v.y + v.z*v.z + v.w*v.w;
    #pragma unroll
    for (int off = 32; off > 0; off >>= 1) {
        s  += __shfl_xor(s,  off, 64);
        s2 += __shfl_xor(s2, off, 64);
    }
    float mean = s * (1.0f / 256.0f);
    float var  = s2 * (1.0f / 256.0f) - mean * mean;
    float rstd = rsqrtf(var + 1e-5f);
    int c0 = lane * 4;
    float4 gg  = *(const float4*)(g + c0);
    float4 bb4 = *(const float4*)(b + c0);
    ushort4 o;
    o.x = f2bf((v.x - mean) * rstd * gg.x + bb4.x);
    o.y = f2bf((v.y - mean) * rstd * gg.y + bb4.y);
    o.z = f2bf((v.z - mean) * rstd * gg.z + bb4.z);
    o.w = f2bf((v.w - mean) * rstd * gg.w + bb4.w);
    *(ushort4*)(out + (size_t)row * 256 + c0) = o;
}

// ---------- tiled MFMA GEMM (QKV / WO): C[M,N] = A[M,K] * Bw[N,K]^T + bias ----------
// 128x128 tile, BK=32 dbuf pipeline, R6 vectorized LDS-staged epilogue.
// MODE 0: bf16   MODE 2: window-reverse scatter + fp32 residual -> bf16
template<int MODE, int K>
__global__ __launch_bounds__(256, 4) void gemm_tile(
        const unsigned short* __restrict__ A,
        const unsigned short* __restrict__ Bw,
        const float* __restrict__ bias,
        int M, int N,
        unsigned short* __restrict__ obf,
        float* __restrict__ of32,
        const void* __restrict__ addp) {
    __shared__ __align__(16) char smem_raw[64 * 132 * 4];   // 33792B: max(dbuf 32KB, C-stage 64x132 f32)
    unsigned short* sm = (unsigned short*)smem_raw;
    float* cst = (float*)smem_raw;
    const int t = threadIdx.x;
    const int lane = t & 63, wave = t >> 6;
    const int m0 = blockIdx.x * 128, n0 = blockIdx.y * 128;
    const int wm = (wave >> 1) * 64, wn = (wave & 1) * 64;
    const int lr = lane & 15, kg = lane >> 4;

    f32x4_t acc[4][4];
    #pragma unroll
    for (int i = 0; i < 4; ++i)
        #pragma unroll
        for (int j = 0; j < 4; ++j) { acc[i][j][0]=0.f; acc[i][j][1]=0.f; acc[i][j][2]=0.f; acc[i][j][3]=0.f; }

    const unsigned short* ga = A  + (size_t)(m0 + (t >> 2)) * K + (t & 3) * 8;
    const unsigned short* gb = Bw + (size_t)(n0 + (t >> 2)) * K + (t & 3) * 8;
    unsigned short* lA = sm + t * 8;
    unsigned short* lB = sm + 4096 + t * 8;

    const int NT = K / 32;
    g2lds16(ga,                  lA);
    g2lds16(ga + (size_t)64 * K, lA + 2048);
    g2lds16(gb,                  lB);
    g2lds16(gb + (size_t)64 * K, lB + 2048);
    __syncthreads();

    #pragma unroll
    for (int k = 0; k < NT; ++k) {
        const int cur = k & 1;
        if (k + 1 < NT) {
            const int nx = cur ^ 1;
            const unsigned short* gA = ga + (k + 1) * 32;
            const unsigned short* gB = gb + (k + 1) * 32;
            g2lds16(gA,                  lA + nx * 8192);
            g2lds16(gA + (size_t)64 * K, lA + nx * 8192 + 2048);
            g2lds16(gB,                  lB + nx * 8192);
            g2lds16(gB + (size_t)64 * K, lB + nx * 8192 + 2048);
        }
        const unsigned short* Ab = sm + cur * 8192;
        const unsigned short* Bb = Ab + 4096;
        bf16x8_t af[4], bfr[4];
        #pragma unroll
        for (int i = 0; i < 4; ++i)
            af[i] = *(const bf16x8_t*)&Ab[(wm + i * 16 + lr) * 32 + kg * 8];
        #pragma unroll
        for (int j = 0; j < 4; ++j)
            bfr[j] = *(const bf16x8_t*)&Bb[(wn + j * 16 + lr) * 32 + kg * 8];
        #pragma unroll
        for (int i = 0; i < 4; ++i)
            #pragma unroll
            for (int j = 0; j < 4; ++j)
                acc[i][j] = __builtin_amdgcn_mfma_f32_16x16x32_bf16(af[i], bfr[j], acc[i][j], 0, 0, 0);
        __syncthreads();
    }

    // ---- 2-pass vectorized epilogue, wave-contiguous stores ----
    #pragma unroll
    for (int pass = 0; pass < 2; ++pass) {
        __syncthreads();
        if ((wave >> 1) == pass) {
            float* cw = cst + (kg * 4) * 132 + wn + lr;
            #pragma unroll
            for (int i = 0; i < 4; ++i)
                #pragma unroll
                for (int j = 0; j < 4; ++j)
                    #pragma unroll
                    for (int e = 0; e < 4; ++e)
                        cw[(i * 16 + e) * 132 + j * 16] = acc[i][j][e];
        }
        __syncthreads();
        const int rr = t >> 4;
        const int ch = t & 15;
        if (MODE == 0) {
            #pragma unroll
            for (int c = 0; c < 4; ++c) {
                int r = rr + c * 16;
                int grow = m0 + pass * 64 + r;
                const float* cr = cst + r * 132 + ch * 8;
                const float* bp = bias + n0 + ch * 8;
                float4 a   = *(const float4*)(cr);
                float4 b4  = *(const float4*)(cr + 4);
                float4 ba  = *(const float4*)(bp);
                float4 bb4 = *(const float4*)(bp + 4);
                u16x8 o = { f2bf(a.x + ba.x),  f2bf(a.y + ba.y),  f2bf(a.z + ba.z),  f2bf(a.w + ba.w),
                            f2bf(b4.x + bb4.x), f2bf(b4.y + bb4.y), f2bf(b4.z + bb4.z), f2bf(b4.w + bb4.w) };
                *(u16x8*)(obf + (size_t)grow * N + n0 + ch * 8) = o;
            }
        } else {  // MODE 2
            #pragma unroll
            for (int c = 0; c < 4; ++c) {
                int r = rr + c * 16;
                int grow = m0 + pass * 64 + r;
                int bb_ = grow >> 12, rem = grow & 4095;
                int winid = rem >> 6, tok = rem & 63;
                int wi = winid >> 3, wj = winid & 7;
                int ii = tok >> 3,  jj = tok & 7;
                int hh = (wi * 8 + ii + 4) & 63;   // roll(+4)
                int ww = (wj * 8 + jj + 4) & 63;
                size_t drow = (size_t)(bb_ << 12) + hh * 64 + ww;
                const float* cr = cst + r * 132 + ch * 8;
                const float* bp = bias + n0 + ch * 8;
                const float* res = (const float*)addp + drow * N + n0 + ch * 8;
                float4 a   = *(const float4*)(cr);
                float4 b4  = *(const float4*)(cr + 4);
                float4 ba  = *(const float4*)(bp);
                float4 bb4 = *(const float4*)(bp + 4);
                float4 ra  = *(const float4*)(res);
                float4 rb  = *(const float4*)(res + 4);
                u16x8 o = { f2bf(a.x + ba.x + ra.x),  f2bf(a.y + ba.y + ra.y),
                            f2bf(a.z + ba.z + ra.z),  f2bf(a.w + ba.w + ra.w),
                            f2bf(b4.x + bb4.x + rb.x), f2bf(b4.y + bb4.y + rb.y),
                            f2bf(b4.z + bb4.z + rb.z), f2bf(b4.w + bb4.w + rb.w) };
                *(u16x8*)(obf + drow * N + n0 + ch * 8) = o;
            }
        }
    }
}

// ---------- fused LN2 + MLP-up + GELU + MLP-down + residual ----------
// Block = 128 tokens, 256 threads (4 waves, wave owns 32 rows). x kept in registers
// as MFMA A-frags (LN folded: h1 = rsig*(x@w1g) - mu*rsig*s1[n] + b1p[n]).
// Per 32-wide hidden chunk: GEMM1 -> gelu -> wave-local LDS bounce -> GEMM2 accum.
// Weights double-buffered via global_load_lds (L2-resident); one barrier per round
// (prefetch covered by ~600cy compute -- the coverage a bare 2-barrier GEMM lacks).
// LDS (dynamic 75776B): w1c 2x16K [8kk][32n][32k] | w2c 2x16K [256n][32k] |
// h1c 4x2560 [32r][40k-padded] ; prologue x-temp overlay @0 (64K);
// epilogue cst overlay @0 ([64][260] f32).
__global__ __launch_bounds__(256, 1) void fused_mlp(
        const unsigned short* __restrict__ hb,   // [32768][256] bf16 residual state
        const unsigned short* __restrict__ w1g,  // [1024][256] bf16 (gamma-scaled)
        const unsigned short* __restrict__ w2b,  // [256][1024] bf16
        const float* __restrict__ s1,            // [1024]
        const float* __restrict__ b1p,           // [1024]
        const float* __restrict__ b2,            // [256]
        float* __restrict__ out) {               // [32768][256] f32
    extern __shared__ __align__(16) char sm[];
    unsigned short* w1c = (unsigned short*)sm;             // + buf*8192 elems
    unsigned short* w2c = (unsigned short*)(sm + 32768);   // + buf*8192 elems
    unsigned short* h1c = (unsigned short*)(sm + 65536);   // + wave*1280 elems
    const int t = threadIdx.x, lane = t & 63, wave = t >> 6;
    const int lr = lane & 15, quad = lane >> 4;            // quad == kg
    const size_t rowbase = (size_t)blockIdx.x * 128;

    // ---- prologue: load x (raw bf16), row stats, bounce to A-frags ----
    const int xr = t >> 1, xh = t & 1;                     // row 0..127, half 0..1
    float s = 0.f, s2 = 0.f;
    {
        const unsigned short* xp = hb + (rowbase + xr) * 256 + xh * 128;
        u16x8 xf[16];
        #pragma unroll
        for (int f = 0; f < 16; ++f) {
            xf[f] = *(const u16x8*)(xp + f * 8);
            #pragma unroll
            for (int e = 0; e < 8; ++e) { float v = bfu(xf[f][e]); s += v; s2 += v * v; }
        }
        unsigned short* xt = (unsigned short*)sm;          // x-temp [8 kk][128 r][32 k]
        #pragma unroll
        for (int f = 0; f < 16; ++f) {
            int kk = xh * 4 + (f >> 2), kw = (f & 3) * 8;
            *(u16x8*)(xt + kk * 4096 + xr * 32 + kw) = xf[f];
        }
    }
    s  += __shfl_xor(s, 1, 64);
    s2 += __shfl_xor(s2, 1, 64);
    float mean = s * (1.0f / 256.0f);
    float var  = s2 * (1.0f / 256.0f) - mean * mean;
    float v_rst  = rsqrtf(var + 1e-5f);
    float v_murs = mean * v_rst;
    __syncthreads();

    bf16x8_t xa[2][8];
    {
        const unsigned short* xt = (const unsigned short*)sm;
        #pragma unroll
        for (int rs = 0; rs < 2; ++rs)
            #pragma unroll
            for (int kk = 0; kk < 8; ++kk)
                xa[rs][kk] = *(const bf16x8_t*)(xt + kk * 4096 + (wave * 32 + rs * 16 + lr) * 32 + quad * 8);
    }
    float murs[2][4], rstv[2][4];
    #pragma unroll
    for (int rs = 0; rs < 2; ++rs)
        #pragma unroll
        for (int e = 0; e < 4; ++e) {
            int srcl = 2 * (rs * 16 + quad * 4 + e);
            murs[rs][e] = __shfl(v_murs, srcl, 64);
            rstv[rs][e] = __shfl(v_rst,  srcl, 64);
        }
    __syncthreads();   // all x-temp reads done before staging overwrites

    // ---- staging helper (8 g2lds/thread/round; L2-resident weights) ----
    auto stage = [&](int c, int buf) {
        #pragma unroll
        for (int i = 0; i < 4; ++i) {
            int n1 = (t >> 2) & 31, kk1 = i * 2 + (t >> 7), kw = (t & 3) * 8;
            g2lds16(w1g + (size_t)(c * 32 + n1) * 256 + kk1 * 32 + kw,
                    w1c + buf * 8192 + i * 2048 + t * 8);
            int n2 = i * 64 + (t >> 2);
            g2lds16(w2b + (size_t)n2 * 1024 + c * 32 + kw,
                    w2c + buf * 8192 + i * 2048 + t * 8);
        }
    };
    stage(0, 0);

    f32x4_t zz[2][16];
    #pragma unroll
    for (int rs = 0; rs < 2; ++rs)
        #pragma unroll
        for (int cs = 0; cs < 16; ++cs) { zz[rs][cs][0]=0.f; zz[rs][cs][1]=0.f; zz[rs][cs][2]=0.f; zz[rs][cs][3]=0.f; }
    __syncthreads();   // buf0 staged

    unsigned short* H = h1c + wave * 1280;   // [32][40] padded
    for (int c = 0; c < 32; ++c) {
        const int cur = c & 1;
        if (c + 1 < 32) stage(c + 1, cur ^ 1);
        const unsigned short* W1 = w1c + cur * 8192;
        const unsigned short* W2 = w2c + cur * 8192;
        // GEMM1: 32 rows x 32 hidden, K=256 (A from regs)
        f32x4_t a1[2][2];
        #pragma unroll
        for (int rs = 0; rs < 2; ++rs)
            #pragma unroll
            for (int ns = 0; ns < 2; ++ns) { a1[rs][ns][0]=0.f; a1[rs][ns][1]=0.f; a1[rs][ns][2]=0.f; a1[rs][ns][3]=0.f; }
        #pragma unroll
        for (int kk = 0; kk < 8; ++kk) {
            bf16x8_t b0 = *(const bf16x8_t*)&W1[kk * 1024 + lr * 32 + quad * 8];
            bf16x8_t b1f = *(const bf16x8_t*)&W1[kk * 1024 + (16 + lr) * 32 + quad * 8];
            a1[0][0] = __builtin_amdgcn_mfma_f32_16x16x32_bf16(xa[0][kk], b0,  a1[0][0], 0, 0, 0);
            a1[0][1] = __builtin_amdgcn_mfma_f32_16x16x32_bf16(xa[0][kk], b1f, a1[0][1], 0, 0, 0);
            a1[1][0] = __builtin_amdgcn_mfma_f32_16x16x32_bf16(xa[1][kk], b0,  a1[1][0], 0, 0, 0);
            a1[1][1] = __builtin_amdgcn_mfma_f32_16x16x32_bf16(xa[1][kk], b1f, a1[1][1], 0, 0, 0);
        }
        // LN-fold + bias + gelu -> bf16 -> wave-local h1c
        float s1v[2], b1v[2];
        #pragma unroll
        for (int ns = 0; ns < 2; ++ns) {
            int col = c * 32 + ns * 16 + lr;
            s1v[ns] = s1[col];
            b1v[ns] = b1p[col];
        }
        #pragma unroll
        for (int rs = 0; rs < 2; ++rs)
            #pragma unroll
            for (int ns = 0; ns < 2; ++ns)
                #pragma unroll
                for (int e = 0; e < 4; ++e) {
                    float h = rstv[rs][e] * a1[rs][ns][e] - murs[rs][e] * s1v[ns] + b1v[ns];
                    H[(rs * 16 + quad * 4 + e) * 40 + ns * 16 + lr] = f2bf(gelu_t(h));
                }
        __asm__ volatile("s_waitcnt lgkmcnt(0)" ::: "memory");
        // GEMM2: 32 rows x 256 out, K=32 (accumulate)
        bf16x8_t pa0 = *(const bf16x8_t*)&H[lr * 40 + quad * 8];
        bf16x8_t pa1 = *(const bf16x8_t*)&H[(16 + lr) * 40 + quad * 8];
        #pragma unroll
        for (int cs = 0; cs < 16; ++cs) {
            bf16x8_t vb = *(const bf16x8_t*)&W2[(cs * 16 + lr) * 32 + quad * 8];
            zz[0][cs] = __builtin_amdgcn_mfma_f32_16x16x32_bf16(pa0, vb, zz[0][cs], 0, 0, 0);
            zz[1][cs] = __builtin_amdgcn_mfma_f32_16x16x32_bf16(pa1, vb, zz[1][cs], 0, 0, 0);
        }
        __syncthreads();   // next-buf staged (drained) + all reads of cur done
    }

    // ---- epilogue: z + b2 + residual -> fp32 out (2 passes via LDS [64][260]) ----
    float* cst = (float*)sm;
    #pragma unroll
    for (int pass = 0; pass < 2; ++pass) {
        __syncthreads();
        if ((wave >> 1) == pass) {
            #pragma unroll
            for (int rs = 0; rs < 2; ++rs)
                #pragma unroll
                for (int cs = 0; cs < 16; ++cs)
                    #pragma unroll
                    for (int e = 0; e < 4; ++e)
                        cst[((wave & 1) * 32 + rs * 16 + quad * 4 + e) * 260 + cs * 16 + lr] = zz[rs][cs][e];
        }
        __syncthreads();
        const int r = t >> 2, q = t & 3;
        size_t grow = rowbase + pass * 64 + r;
        const float* cr = cst + r * 260 + q * 64;
        const unsigned short* rp = hb + grow * 256 + q * 64;
        float* op = out + grow * 256 + q * 64;
        #pragma unroll
        for (int c4 = 0; c4 < 16; ++c4) {
            float4 a  = *(const float4*)(cr + c4 * 4);
            float4 bb = *(const float4*)(b2 + q * 64 + c4 * 4);
            ushort4 rv = *(const ushort4*)(rp + c4 * 4);
            float4 o = { a.x + bb.x + bfu(rv.x), a.y + bb.y + bfu(rv.y),
                         a.z + bb.z + bfu(rv.z), a.w + bb.w + bfu(rv.w) };
            *(float4*)(op + c4 * 4) = o;
        }
    }
}

// ---------- MFMA attention: 4 waves/block, each wave one (window-batch, head) ----------
#define PR 72
#define VR 72
__global__ void __launch_bounds__(256) attn_mfma(
        const unsigned short* __restrict__ qkv,
        const float* __restrict__ relt,
        unsigned short* __restrict__ ctx) {
    __shared__ float rs[1800];
    __shared__ unsigned short Pl[4][64 * PR];
    __shared__ unsigned short Vt[4][32 * VR];

    int t = threadIdx.x;
    int lane = t & 63, wave = t >> 6;
    for (int i = t; i < 1800; i += 256) rs[i] = relt[i];
    __syncthreads();

    int wh = blockIdx.x * 4 + wave;
    int wg = wh >> 3, h = wh & 7;
    int win = wg & 63;
    int ln = lane & 15, quad = lane >> 4;

    unsigned short* P = &Pl[wave][0];
    unsigned short* V = &Vt[wave][0];
    const unsigned short* base = qkv + (size_t)wg * 64 * 768 + h * 32;

    union BF8 { bf16x8_t v; unsigned short s[8]; };
    {
        const bf16x8_t* vp = (const bf16x8_t*)(base + (size_t)lane * 768 + 512);
        BF8 vv[4];
        #pragma unroll
        for (int c = 0; c < 4; ++c) vv[c].v = vp[c];
        #pragma unroll
        for (int c = 0; c < 4; ++c)
            #pragma unroll
            for (int e = 0; e < 8; ++e)
                V[(c * 8 + e) * VR + lane] = vv[c].s[e];
    }

    bf16x8_t qa[4], kb[4];
    #pragma unroll
    for (int i = 0; i < 4; ++i)
        qa[i] = *(const bf16x8_t*)(base + (size_t)(i * 16 + ln) * 768 + quad * 8);
    #pragma unroll
    for (int j = 0; j < 4; ++j)
        kb[j] = *(const bf16x8_t*)(base + (size_t)(j * 16 + ln) * 768 + 256 + quad * 8);

    f32x4_t acc[4][4];
    #pragma unroll
    for (int i = 0; i < 4; ++i)
        #pragma unroll
        for (int j = 0; j < 4; ++j) { acc[i][j][0]=0.f; acc[i][j][1]=0.f; acc[i][j][2]=0.f; acc[i][j][3]=0.f; }
    #pragma unroll
    for (int i = 0; i < 4; ++i)
        #pragma unroll
        for (int j = 0; j < 4; ++j)
            acc[i][j] = __builtin_amdgcn_mfma_f32_16x16x32_bf16(qa[i], kb[j], acc[i][j], 0, 0, 0);

    const float scale = 0.17677669529663687f;
    int wi = win >> 3, wj = win & 7;
    int mjv = ln & 7;
    int regm[4], mi[4];
    #pragma unroll
    for (int j = 0; j < 4; ++j) {
        mi[j] = j * 2 + (ln >> 3);
        int hm = wi * 8 + mi[j], wm = wj * 8 + mjv;
        regm[j] = (hm < 56 ? 0 : (hm < 60 ? 1 : 2)) * 3 + (wm < 56 ? 0 : (wm < 60 ? 1 : 2));
    }
    float inv[4][4];
    #pragma unroll
    for (int i = 0; i < 4; ++i) {
        #pragma unroll
        for (int e = 0; e < 4; ++e) {
            int q = i * 16 + quad * 4 + e;
            int ti = q >> 3, tj = q & 7;
            int hn = wi * 8 + ti, wn = wj * 8 + tj;
            int regn = (hn < 56 ? 0 : (hn < 60 ? 1 : 2)) * 3 + (wn < 56 ? 0 : (wn < 60 ? 1 : 2));
            float sum = 0.f;
            #pragma unroll
            for (int j = 0; j < 4; ++j) {
                float bv = rs[((ti - mi[j] + 7) * 15 + (tj - mjv + 7)) * 8 + h];
                float sv = acc[i][j][e] * scale + bv + (regm[j] != regn ? -100.f : 0.f);
                float p = __expf(sv);
                sum += p;
                P[q * PR + j * 16 + ln] = f2bf(p);
            }
            #pragma unroll
            for (int off = 1; off < 16; off <<= 1) sum += __shfl_xor(sum, off, 64);
            inv[i][e] = 1.0f / sum;
        }
    }
    __syncthreads();

    bf16x8_t vb[2][2];
    #pragma unroll
    for (int jd = 0; jd < 2; ++jd)
        #pragma unroll
        for (int kc = 0; kc < 2; ++kc)
            vb[jd][kc] = *(const bf16x8_t*)&V[(jd * 16 + ln) * VR + kc * 32 + quad * 8];
    f32x4_t occ[4][2];
    #pragma unroll
    for (int i = 0; i < 4; ++i)
        #pragma unroll
        for (int jd = 0; jd < 2; ++jd) { occ[i][jd][0]=0.f; occ[i][jd][1]=0.f; occ[i][jd][2]=0.f; occ[i][jd][3]=0.f; }
    #pragma unroll
    for (int i = 0; i < 4; ++i) {
        #pragma unroll
        for (int kc = 0; kc < 2; ++kc) {
            bf16x8_t pf = *(const bf16x8_t*)&P[(i * 16 + ln) * PR + kc * 32 + quad * 8];
            occ[i][0] = __builtin_amdgcn_mfma_f32_16x16x32_bf16(pf, vb[0][kc], occ[i][0], 0, 0, 0);
            occ[i][1] = __builtin_amdgcn_mfma_f32_16x16x32_bf16(pf, vb[1][kc], occ[i][1], 0, 0, 0);
        }
    }

    unsigned short* cbase = ctx + (size_t)wg * 64 * 256 + h * 32;
    #pragma unroll
    for (int i = 0; i < 4; ++i)
        #pragma unroll
        for (int e = 0; e < 4; ++e) {
            int q = i * 16 + quad * 4 + e;
            #pragma unroll
            for (int jd = 0; jd < 2; ++jd)
                cbase[(size_t)q * 256 + jd * 16 + ln] = f2bf(occ[i][jd][e] * inv[i][e]);
        }
}

// ---------- launch ----------
extern "C" void kernel_launch(void* const* d_in, const int* in_sizes, int n_in,
                              void* d_out, int out_size, void* d_ws, size_t ws_size,
                              hipStream_t stream) {
    const float* hs   = (const float*)d_in[0];
    const float* ln1g = (const float*)d_in[1];
    const float* ln1b = (const float*)d_in[2];
    const float* wq   = (const float*)d_in[3];
    const float* bq   = (const float*)d_in[4];
    const float* wk   = (const float*)d_in[5];
    const float* bk   = (const float*)d_in[6];
    const float* wv   = (const float*)d_in[7];
    const float* bv   = (const float*)d_in[8];
    const float* relt = (const float*)d_in[9];
    const float* wo   = (const float*)d_in[10];
    const float* bo   = (const float*)d_in[11];
    const float* ln2g = (const float*)d_in[12];
    const float* ln2b = (const float*)d_in[13];
    const float* w1   = (const float*)d_in[14];
    const float* b1   = (const float*)d_in[15];
    const float* w2   = (const float*)d_in[16];
    const float* b2   = (const float*)d_in[17];
    float* out = (float*)d_out;

    const size_t NTOK = 32768;
    size_t off = 0;
    auto carve = [&](size_t bytes) { void* p = (char*)d_ws + off; off += (bytes + 255) & ~(size_t)255; return p; };
    unsigned short* wqkv_b = (unsigned short*)carve(768ull * 256 * 2);
    unsigned short* wo_b   = (unsigned short*)carve(65536ull * 2);
    unsigned short* w1_b   = (unsigned short*)carve(262144ull * 2);   // gamma-scaled w1 bf16
    unsigned short* w2_b   = (unsigned short*)carve(262144ull * 2);
    float*          bqkv   = (float*)carve(768ull * 4);
    float*          s1w    = (float*)carve(1024ull * 4);
    float*          b1w    = (float*)carve(1024ull * 4);
    unsigned short* hiddenb= (unsigned short*)carve(NTOK * 256 * 2);  // bf16 residual state
    unsigned short* xw     = (unsigned short*)carve(NTOK * 256 * 2);
    unsigned short* qkvb   = (unsigned short*)carve(NTOK * 768 * 2);  // q|k|v
    unsigned short* cx     = (unsigned short*)carve(NTOK * 256 * 2);

    static bool attr_set = false;
    if (!attr_set) {
        hipFuncSetAttribute(reinterpret_cast<const void*>(fused_mlp),
                            hipFuncAttributeMaxDynamicSharedMemorySize, 75776);
        attr_set = true;
    }

    // 1) weights -> bf16 (w1 gamma-folded); biases packed; LN2-fold row sums
    cvt_all<<<768, 256, 0, stream>>>(wq, wk, wv, wo, w1, w2, ln2g, wqkv_b, wo_b, w1_b, w2_b);
    prep_mlp<<<4, 256, 0, stream>>>(w1, ln2g, ln2b, b1, s1w, b1w);
    hipMemcpyAsync(bqkv,       bq, 256 * 4, hipMemcpyDeviceToDevice, stream);
    hipMemcpyAsync(bqkv + 256, bk, 256 * 4, hipMemcpyDeviceToDevice, stream);
    hipMemcpyAsync(bqkv + 512, bv, 256 * 4, hipMemcpyDeviceToDevice, stream);

    // 2) LN1 + cyclic shift + window partition -> xw (bf16)
    ln_kernel<1, 0><<<8192, 256, 0, stream>>>(hs, ln1g, ln1b, xw);

    // 3) fused QKV projection
    gemm_tile<0, 256><<<dim3(256, 6), 256, 0, stream>>>(xw, wqkv_b, bqkv, 32768, 768, qkvb, nullptr, nullptr);

    // 4) windowed MFMA attention
    attn_mfma<<<1024, 256, 0, stream>>>(qkvb, relt, cx);

    // 5) out projection + window reverse + unshift + fp32 residual -> hiddenb (bf16)
    gemm_tile<2, 256><<<dim3(256, 2), 256, 0, stream>>>(cx, wo_b, bo, 32768, 256, hiddenb, nullptr, hs);

    // 6-8) fused LN2 + MLP (up+gelu+down) + residual -> out (fp32)
    fused_mlp<<<256, 256, 75776, stream>>>(hiddenb, w1_b, w2_b, s1w, b1w, b2, out);
}